// Round 4
// baseline (336.008 us; speedup 1.0000x reference)
//
#include <hip/hip_runtime.h>
#include <float.h>
#include <limits.h>

// RankLoss round 4: uniform 500-float units + register-resident 4-buffer
// software pipeline (loads 3 units ahead), launch_bounds(256,4) for 128 VGPRs.
// R3 failed because the compiler spilled the prefetch buffer (WRITE_SIZE
// 1.5->42.6 MB, VGPR=32); this version has no struct copies/arrays and a
// 1-unit = 8-VGPR footprint. argmax/dup via ballot (positions monotone in
// lane); x[target] gather moved to the tiny combine kernel.

constexpr int B     = 32768;
constexpr int C_ENT = 1000;
constexpr int C_REL = 500;
constexpr int NU    = 163840;       // 2*B (s halves) + 2*B (o halves) + B (r)
constexpr int UPW   = 16;           // units per wave
constexpr float LOG2E = 1.4426950408889634f;

__device__ inline float fast_exp2(float x) { return exp2f(x); }

// unit u -> base pointer (16B-aligned: 500 floats = 2000 B) and row-index offset
__device__ inline const float4* unit_ptr(int u, const float* s, const float* r,
                                         const float* o) {
  const float* p;
  if (u < 2 * B)        p = s + ((size_t)(u >> 1) * C_ENT + (size_t)(u & 1) * C_REL);
  else if (u < 4 * B) { int v = u - 2 * B;
                        p = o + ((size_t)(v >> 1) * C_ENT + (size_t)(v & 1) * C_REL); }
  else                  p = r + (size_t)(u - 4 * B) * C_REL;
  return (const float4*)p;
}
__device__ inline int unit_ioff(int u) { return (u < 4 * B) ? (u & 1) * C_REL : 0; }

// lane l owns floats 8l..8l+7 (positions monotone in lane -> ballot argmax works)
__device__ inline void unit_load(const float4* p4, int lane, float4& va, float4& vb) {
  va = make_float4(-FLT_MAX, -FLT_MAX, -FLT_MAX, -FLT_MAX);
  vb = va;
  if (lane <= 62) va = p4[2 * lane];        // float4 idx 2l   < 125
  if (lane <= 61) vb = p4[2 * lane + 1];    // float4 idx 2l+1 < 125
}

__device__ inline float4 unit_compute(const float4 va, const float4 vb,
                                      int lane, int ioff) {
  // ---- m1: tree + 6-stage butterfly ----
  float m = fmaxf(fmaxf(fmaxf(va.x, va.y), fmaxf(va.z, va.w)),
                  fmaxf(fmaxf(vb.x, vb.y), fmaxf(vb.z, vb.w)));
#pragma unroll
  for (int off = 32; off; off >>= 1) m = fmaxf(m, __shfl_xor(m, off));
  const float m1 = m;
  const float nm1l = -m1 * LOG2E;

  // ---- exp-sum (sentinels: fma -> -inf -> exp2 = 0) ----
  float z = (fast_exp2(fmaf(va.x, LOG2E, nm1l)) + fast_exp2(fmaf(va.y, LOG2E, nm1l))) +
            (fast_exp2(fmaf(va.z, LOG2E, nm1l)) + fast_exp2(fmaf(va.w, LOG2E, nm1l))) +
            (fast_exp2(fmaf(vb.x, LOG2E, nm1l)) + fast_exp2(fmaf(vb.y, LOG2E, nm1l))) +
            (fast_exp2(fmaf(vb.z, LOG2E, nm1l)) + fast_exp2(fmaf(vb.w, LOG2E, nm1l)));

  // ---- eq-masked m2, holder count, lowest in-lane holder position ----
  const bool e0 = (va.x == m1), e1 = (va.y == m1), e2 = (va.z == m1), e3 = (va.w == m1);
  const bool e4 = (vb.x == m1), e5 = (vb.y == m1), e6 = (vb.z == m1), e7 = (vb.w == m1);
  const int cnt = ((int)e0 + (int)e1 + (int)e2 + (int)e3) +
                  ((int)e4 + (int)e5 + (int)e6 + (int)e7);
  float m2 = fmaxf(fmaxf(fmaxf(e0 ? -FLT_MAX : va.x, e1 ? -FLT_MAX : va.y),
                         fmaxf(e2 ? -FLT_MAX : va.z, e3 ? -FLT_MAX : va.w)),
                   fmaxf(fmaxf(e4 ? -FLT_MAX : vb.x, e5 ? -FLT_MAX : vb.y),
                         fmaxf(e6 ? -FLT_MAX : vb.z, e7 ? -FLT_MAX : vb.w)));
  const int li = e0 ? 0 : e1 ? 1 : e2 ? 2 : e3 ? 3 : e4 ? 4 : e5 ? 5 : e6 ? 6 : 7;

  // ---- argmax + dup via ballot (positions monotone in lane) ----
  const unsigned long long b1 = __ballot(cnt >= 1);
  const unsigned long long b2 = __ballot(cnt >= 2);
  const bool dup = (__popcll(b1) >= 2) || (b2 != 0ULL);
  const int src = __ffsll(b1) - 1;                 // b1 != 0 always
  const int gidx = ioff + 8 * src + __shfl(li, src);

  // ---- Z-sum + m2-max butterfly (interleaved, independent) ----
#pragma unroll
  for (int off = 32; off; off >>= 1) {
    z += __shfl_xor(z, off);
    m2 = fmaxf(m2, __shfl_xor(m2, off));
  }
  if (dup) m2 = m1;   // max value duplicated -> second value == max

  return make_float4(m1, m2, z, __int_as_float(gidx));
}

// grid = NU/UPW/4 blocks x 256. Explicit 4-buffer rotation, 3 loads in flight.
__global__ __launch_bounds__(256, 4) void stats_kernel(
    const float* __restrict__ s, const float* __restrict__ r, const float* __restrict__ o,
    float4* __restrict__ out4) {
  const int lane = threadIdx.x & 63;
  const int u0 = (blockIdx.x * 4 + (threadIdx.x >> 6)) * UPW;

  float4 Aa, Ab, Ba, Bb, Ca, Cb, Da, Db;
  unit_load(unit_ptr(u0 + 0, s, r, o), lane, Aa, Ab);
  unit_load(unit_ptr(u0 + 1, s, r, o), lane, Ba, Bb);
  unit_load(unit_ptr(u0 + 2, s, r, o), lane, Ca, Cb);

#pragma unroll
  for (int j = 0; j < UPW; j += 4) {
    float4 res;
    if (j + 3 < UPW) unit_load(unit_ptr(u0 + j + 3, s, r, o), lane, Da, Db);
    res = unit_compute(Aa, Ab, lane, unit_ioff(u0 + j + 0));
    if (lane == 0) out4[u0 + j + 0] = res;
    if (j + 4 < UPW) unit_load(unit_ptr(u0 + j + 4, s, r, o), lane, Aa, Ab);
    res = unit_compute(Ba, Bb, lane, unit_ioff(u0 + j + 1));
    if (lane == 0) out4[u0 + j + 1] = res;
    if (j + 5 < UPW) unit_load(unit_ptr(u0 + j + 5, s, r, o), lane, Ba, Bb);
    res = unit_compute(Ca, Cb, lane, unit_ioff(u0 + j + 2));
    if (lane == 0) out4[u0 + j + 2] = res;
    if (j + 6 < UPW) unit_load(unit_ptr(u0 + j + 6, s, r, o), lane, Ca, Cb);
    res = unit_compute(Da, Db, lane, unit_ioff(u0 + j + 3));
    if (lane == 0) out4[u0 + j + 3] = res;
  }
}

// merge two half-row stats: top2 of union + rescaled Z + idx (half1 idx already +500)
__device__ inline void merge_halves(float4 a, float4 b,
                                    float& m1, float& m2, float& Z, int& idx) {
  m1 = fmaxf(a.x, b.x);
  Z  = a.z * fast_exp2((a.x - m1) * LOG2E) + b.z * fast_exp2((b.x - m1) * LOG2E);
  m2 = fmaxf(fminf(a.x, b.x), (a.x >= b.x) ? a.y : b.y);   // ==-case -> m2 = m1 (dup)
  idx = (b.x > a.x) ? __float_as_int(b.w) : __float_as_int(a.w);  // tie -> half0 (lower)
}

__global__ __launch_bounds__(256) void combine_kernel(
    const float4* __restrict__ st4,
    const float* __restrict__ s, const float* __restrict__ r, const float* __restrict__ o,
    const int* __restrict__ st, const int* __restrict__ rt, const int* __restrict__ ot,
    float* __restrict__ out) {
  const int row = blockIdx.x * 256 + threadIdx.x;   // grid = B/256

  const float4 sa = st4[2 * row],         sb = st4[2 * row + 1];
  const float4 oa = st4[2 * B + 2 * row], ob = st4[2 * B + 2 * row + 1];
  const float4 rr = st4[4 * B + row];
  const int ts = st[row], tr = rt[row], to = ot[row];
  const float xs = s[(size_t)row * C_ENT + ts];
  const float xr = r[(size_t)row * C_REL + tr];
  const float xo = o[(size_t)row * C_ENT + to];

  float sm1, sm2, sZ; int si;
  float om1, om2, oZ; int oi;
  merge_halves(sa, sb, sm1, sm2, sZ, si);
  merge_halves(oa, ob, om1, om2, oZ, oi);
  const float rm1 = rr.x, rm2 = rr.y, rZ = rr.z;
  const int ri = __float_as_int(rr.w);

  const float sI = 1.0f / sZ, rI = 1.0f / rZ, oI = 1.0f / oZ;
  const float sp1 = fast_exp2((sm2 - sm1) * LOG2E) * sI;
  const float rp1 = fast_exp2((rm2 - rm1) * LOG2E) * rI;
  const float op1 = fast_exp2((om2 - om1) * LOG2E) * oI;
  const float spt = fast_exp2((xs - sm1) * LOG2E) * sI;
  const float rpt = fast_exp2((xr - rm1) * LOG2E) * rI;
  const float opt = fast_exp2((xo - om1) * LOG2E) * oI;

  const float gt   = spt * rpt * opt;
  const float top1 = sI * rI * oI;
  // second-smallest of the 8 top2-products = min of the three one-swap products
  const float c1 = sI  * rp1 * op1;
  const float c2 = sp1 * rI  * op1;
  const float c3 = sp1 * rp1 * oI;
  const float second = fminf(c1, fminf(c2, c3));
  const bool cond = (si == ts) && (ri == tr) && (oi == to);
  const float pre = cond ? second : top1;
  float val = fmaxf(1.0f - gt + pre, 0.0f) * (1.0f / (float)B);

  // block reduction -> one atomic per block (out zeroed by memset in launcher)
#pragma unroll
  for (int off = 32; off; off >>= 1) val += __shfl_xor(val, off);
  __shared__ float lds[4];
  if ((threadIdx.x & 63) == 0) lds[threadIdx.x >> 6] = val;
  __syncthreads();
  if (threadIdx.x == 0)
    atomicAdd(out, (lds[0] + lds[1]) + (lds[2] + lds[3]));
}

// ---------------- fallback (ws too small): one wave per row, atomic ----------------

__device__ inline void combine_stats(float& m1, int& i1, float& m2, float& Z,
                                     float bm1, int bi1, float bm2, float bZ) {
  bool bwin = (bm1 > m1) || (bm1 == m1 && bi1 < i1);
  float wm1 = bwin ? bm1 : m1;
  int   wi1 = bwin ? bi1 : i1;
  float wm2 = bwin ? bm2 : m2;
  float lm1 = bwin ? m1  : bm1;
  float wZ  = bwin ? bZ  : Z;
  float lZ  = bwin ? Z   : bZ;
  m1 = wm1; i1 = wi1;
  m2 = fmaxf(wm2, lm1);
  Z  = wZ + lZ * __expf(lm1 - wm1);
}

template<int NK, int C4>
__device__ inline void row_stats(const float* __restrict__ row, int lane, int target,
                                 float& p_top1, float& p_top2, int& amax, float& p_tgt) {
  const float4* row4 = (const float4*)row;
  float4 v[NK];
#pragma unroll
  for (int k = 0; k < NK; ++k) {
    int idx = lane + 64 * k;
    v[k] = (idx < C4) ? row4[idx] : make_float4(-FLT_MAX, -FLT_MAX, -FLT_MAX, -FLT_MAX);
  }
  float m1 = -FLT_MAX, m2 = -FLT_MAX;
  int   i1 = 0x7fffffff;
#pragma unroll
  for (int k = 0; k < NK; ++k) {
    int base = 4 * (lane + 64 * k);
    float a0 = v[k].x, a1 = v[k].y, a2 = v[k].z, a3 = v[k].w;
    if (a0 > m1) { m2 = m1; m1 = a0; i1 = base;     } else if (a0 > m2) m2 = a0;
    if (a1 > m1) { m2 = m1; m1 = a1; i1 = base + 1; } else if (a1 > m2) m2 = a1;
    if (a2 > m1) { m2 = m1; m1 = a2; i1 = base + 2; } else if (a2 > m2) m2 = a2;
    if (a3 > m1) { m2 = m1; m1 = a3; i1 = base + 3; } else if (a3 > m2) m2 = a3;
  }
  float Z = 0.f;
#pragma unroll
  for (int k = 0; k < NK; ++k) {
    Z += __expf(v[k].x - m1); Z += __expf(v[k].y - m1);
    Z += __expf(v[k].z - m1); Z += __expf(v[k].w - m1);
  }
#pragma unroll
  for (int off = 32; off > 0; off >>= 1) {
    float bm1 = __shfl_xor(m1, off);
    int   bi1 = __shfl_xor(i1, off);
    float bm2 = __shfl_xor(m2, off);
    float bZ  = __shfl_xor(Z,  off);
    combine_stats(m1, i1, m2, Z, bm1, bi1, bm2, bZ);
  }
  float invZ = 1.0f / Z;
  float xt   = row[target];
  p_top1 = invZ;
  p_top2 = __expf(m2 - m1) * invZ;
  p_tgt  = __expf(xt - m1) * invZ;
  amax   = i1;
}

__global__ __launch_bounds__(256) void rank_loss_atomic_kernel(
    const float* __restrict__ s, const float* __restrict__ r, const float* __restrict__ o,
    const int* __restrict__ st, const int* __restrict__ rt, const int* __restrict__ ot,
    float* __restrict__ out) {
  const int wid  = threadIdx.x >> 6;
  const int lane = threadIdx.x & 63;
  const int row  = blockIdx.x * 4 + wid;

  const int tS = st[row], tR = rt[row], tO = ot[row];
  float sp0, sp1, spt; int sa;
  float rp0, rp1, rpt; int ra;
  float op0, op1, opt; int oa;
  row_stats<4, C_ENT / 4>(s + (size_t)row * C_ENT, lane, tS, sp0, sp1, sa, spt);
  row_stats<2, C_REL / 4>(r + (size_t)row * C_REL, lane, tR, rp0, rp1, ra, rpt);
  row_stats<4, C_ENT / 4>(o + (size_t)row * C_ENT, lane, tO, op0, op1, oa, opt);

  if (lane == 0) {
    float gt   = spt * rpt * opt;
    float top1 = sp0 * rp0 * op0;
    float c1 = sp0 * rp1 * op1;
    float c2 = sp1 * rp0 * op1;
    float c3 = sp1 * rp1 * op0;
    float second = fminf(c1, fminf(c2, c3));
    bool cond = (sa == tS) && (ra == tR) && (oa == tO);
    float pre = cond ? second : top1;
    atomicAdd(out, fmaxf(1.0f - gt + pre, 0.0f) * (1.0f / (float)B));
  }
}

extern "C" void kernel_launch(void* const* d_in, const int* in_sizes, int n_in,
                              void* d_out, int out_size, void* d_ws, size_t ws_size,
                              hipStream_t stream) {
  const float* s  = (const float*)d_in[0];
  const float* r  = (const float*)d_in[1];
  const float* o  = (const float*)d_in[2];
  const int*   st = (const int*)d_in[3];
  const int*   rt = (const int*)d_in[4];
  const int*   ot = (const int*)d_in[5];
  float* out = (float*)d_out;

  hipMemsetAsync(d_out, 0, sizeof(float), stream);
  if (ws_size >= (size_t)NU * sizeof(float4)) {      // 2.5 MiB
    float4* stat4 = (float4*)d_ws;
    stats_kernel<<<NU / UPW / 4, 256, 0, stream>>>(s, r, o, stat4);
    combine_kernel<<<B / 256, 256, 0, stream>>>(stat4, s, r, o, st, rt, ot, out);
  } else {
    rank_loss_atomic_kernel<<<B / 4, 256, 0, stream>>>(s, r, o, st, rt, ot, out);
  }
}